// Round 1
// baseline (101.511 us; speedup 1.0000x reference)
//
#include <hip/hip_runtime.h>
#include <hip/hip_bf16.h>
#include <math.h>

// Problem constants (match reference: B=4096, H=256, E=256, K=100)
#define BB 4096
#define HH 256
#define EE 256
#define KK 100
#define STILE 16

__device__ __forceinline__ float gelu_exact(float x) {
    // torch nn.GELU default: 0.5*x*(1+erf(x/sqrt(2)))
    return 0.5f * x * (1.0f + erff(x * 0.70710678118654752f));
}

__device__ __forceinline__ float norm_clip(float v, float m, float sd) {
    float z = (v - m) / fmaxf(sd, 1e-8f);
    return fminf(5.0f, fmaxf(-5.0f, z));
}

// Kernel 1: hidden = gelu(z*w1+b1), fused with head histogram.
// One block per sample, one thread per hidden unit.
__global__ __launch_bounds__(256) void hidden_hist_kernel(
    const float* __restrict__ values, const float* __restrict__ means,
    const float* __restrict__ stds, const int* __restrict__ head_idx,
    const float* __restrict__ w1, const float* __restrict__ b1,
    float* __restrict__ hidden, int* __restrict__ counts)
{
    const int b = blockIdx.x;
    const int t = threadIdx.x;
    const float z = norm_clip(values[b], means[b], stds[b]);
    const float x = fmaf(z, w1[t], b1[t]);
    hidden[(size_t)b * HH + t] = gelu_exact(x);
    if (t == 0) atomicAdd(&counts[head_idx[b]], 1);
}

// Kernel 2: exclusive scan over K=100 counts (single 128-thread block).
__global__ __launch_bounds__(128) void scan_kernel(
    const int* __restrict__ counts, int* __restrict__ offsets,
    int* __restrict__ cursor)
{
    __shared__ int buf[128];
    const int t = threadIdx.x;
    const int v = (t < KK) ? counts[t] : 0;
    buf[t] = v;
    __syncthreads();
    for (int d = 1; d < 128; d <<= 1) {
        int x = (t >= d) ? buf[t - d] : 0;
        __syncthreads();
        buf[t] += x;
        __syncthreads();
    }
    if (t < KK) {
        int excl = buf[t] - v;            // exclusive prefix
        offsets[t] = excl;
        cursor[t]  = excl;
        if (t == KK - 1) offsets[KK] = buf[t];
    }
}

// Kernel 3: scatter sample ids into per-head buckets.
__global__ __launch_bounds__(256) void scatter_kernel(
    const int* __restrict__ head_idx, int* __restrict__ cursor,
    int* __restrict__ bucket)
{
    const int b = blockIdx.x * blockDim.x + threadIdx.x;
    if (b < BB) {
        int pos = atomicAdd(&cursor[head_idx[b]], 1);
        bucket[pos] = b;
    }
}

// Kernel 4: bucketed multi-sample GEMV.
// grid = (K, SY). Block 256 threads: thread = output column e.
// Each block instance handles head k, s-tiles blockIdx.y, +SY, ... of 16 samples.
// W element loaded once per 16 samples; hidden read via wave-uniform scalar loads.
__global__ __launch_bounds__(256) void head_gemm_kernel(
    const float* __restrict__ hidden, const int* __restrict__ bucket,
    const int* __restrict__ offsets, const float* __restrict__ W_heads,
    const float* __restrict__ b_heads, float* __restrict__ out)
{
    const int k   = blockIdx.x;
    const int beg = offsets[k];
    const int nk  = offsets[k + 1] - beg;
    const int e   = threadIdx.x;
    const float* __restrict__ Wk = W_heads + (size_t)k * (HH * EE);
    const float bias = b_heads[k * EE + e];

    for (int s0 = blockIdx.y * STILE; s0 < nk; s0 += gridDim.y * STILE) {
        // Sample ids for this tile (wave-uniform -> SGPRs). Tail duplicates s0.
        int sb[STILE];
#pragma unroll
        for (int s = 0; s < STILE; ++s) {
            int idx = s0 + s;
            if (idx >= nk) idx = s0;
            sb[s] = __builtin_amdgcn_readfirstlane(bucket[beg + idx]);
        }

        float acc[STILE];
#pragma unroll
        for (int s = 0; s < STILE; ++s) acc[s] = bias;

        for (int h0 = 0; h0 < HH; h0 += 4) {
            const float wv0 = Wk[(h0 + 0) * EE + e];
            const float wv1 = Wk[(h0 + 1) * EE + e];
            const float wv2 = Wk[(h0 + 2) * EE + e];
            const float wv3 = Wk[(h0 + 3) * EE + e];
#pragma unroll
            for (int s = 0; s < STILE; ++s) {
                const float4 hv =
                    *reinterpret_cast<const float4*>(hidden + (size_t)sb[s] * HH + h0);
                acc[s] = fmaf(hv.x, wv0, acc[s]);
                acc[s] = fmaf(hv.y, wv1, acc[s]);
                acc[s] = fmaf(hv.z, wv2, acc[s]);
                acc[s] = fmaf(hv.w, wv3, acc[s]);
            }
        }

#pragma unroll
        for (int s = 0; s < STILE; ++s) {
            if (s0 + s < nk) out[(size_t)sb[s] * EE + e] = acc[s];
        }
    }
}

// Fallback (only if ws too small): one block per sample, hidden in LDS.
__global__ __launch_bounds__(256) void fallback_kernel(
    const float* __restrict__ values, const float* __restrict__ means,
    const float* __restrict__ stds, const int* __restrict__ head_idx,
    const float* __restrict__ w1, const float* __restrict__ b1,
    const float* __restrict__ W_heads, const float* __restrict__ b_heads,
    float* __restrict__ out)
{
    __shared__ float hid[HH];
    const int b = blockIdx.x;
    const int t = threadIdx.x;
    const float z = norm_clip(values[b], means[b], stds[b]);
    hid[t] = gelu_exact(fmaf(z, w1[t], b1[t]));
    __syncthreads();
    const int k = head_idx[b];
    const float* __restrict__ Wk = W_heads + (size_t)k * (HH * EE);
    float acc = b_heads[k * EE + t];
    for (int h = 0; h < HH; ++h) acc = fmaf(hid[h], Wk[h * EE + t], acc);
    out[(size_t)b * EE + t] = acc;
}

extern "C" void kernel_launch(void* const* d_in, const int* in_sizes, int n_in,
                              void* d_out, int out_size, void* d_ws, size_t ws_size,
                              hipStream_t stream)
{
    const float* values   = (const float*)d_in[0];
    const float* means    = (const float*)d_in[1];
    const float* stds     = (const float*)d_in[2];
    const int*   head_idx = (const int*)d_in[3];
    const float* w1       = (const float*)d_in[4];
    const float* b1       = (const float*)d_in[5];
    const float* W_heads  = (const float*)d_in[6];
    const float* b_heads  = (const float*)d_in[7];
    float* out = (float*)d_out;

    // Workspace layout (bytes):
    //   [0,512)      counts (K ints)
    //   [512,1024)   cursor (K ints)
    //   [1024,2048)  offsets (K+1 ints)
    //   [2048,32768) bucket (B ints)
    //   [32768,...)  hidden (B*H floats)
    const size_t need = 32768 + (size_t)BB * HH * sizeof(float);
    if (ws_size >= need) {
        char* ws = (char*)d_ws;
        int*   counts  = (int*)(ws + 0);
        int*   cursor  = (int*)(ws + 512);
        int*   offsets = (int*)(ws + 1024);
        int*   bucket  = (int*)(ws + 2048);
        float* hidden  = (float*)(ws + 32768);

        hipMemsetAsync(counts, 0, 512, stream);
        hidden_hist_kernel<<<BB, 256, 0, stream>>>(values, means, stds, head_idx,
                                                   w1, b1, hidden, counts);
        scan_kernel<<<1, 128, 0, stream>>>(counts, offsets, cursor);
        scatter_kernel<<<(BB + 255) / 256, 256, 0, stream>>>(head_idx, cursor, bucket);
        head_gemm_kernel<<<dim3(KK, 8), 256, 0, stream>>>(hidden, bucket, offsets,
                                                          W_heads, b_heads, out);
    } else {
        fallback_kernel<<<BB, 256, 0, stream>>>(values, means, stds, head_idx,
                                                w1, b1, W_heads, b_heads, out);
    }
}

// Round 2
// 44.523 us; speedup vs baseline: 2.2799x; 2.2799x over previous
//
#include <hip/hip_runtime.h>
#include <hip/hip_bf16.h>
#include <math.h>

// Problem constants (match reference: B=4096, H=256, E=256, K=100)
#define BB 4096
#define HH 256
#define EE 256
#define KK 100
#define MAXT 5   // s-tile blocks per head (covers nk<=80; loop handles more)

typedef __bf16 bf16x8 __attribute__((ext_vector_type(8)));
typedef float  f32x4  __attribute__((ext_vector_type(4)));

__device__ __forceinline__ float gelu_exact(float x) {
    return 0.5f * x * (1.0f + erff(x * 0.70710678118654752f));
}

__device__ __forceinline__ float norm_clip(float v, float m, float sd) {
    float z = (v - m) / fmaxf(sd, 1e-8f);
    return fminf(5.0f, fmaxf(-5.0f, z));
}

// Kernel 1: hidden = gelu(z*w1+b1) in bf16, fused with head histogram.
// grid = B/16 blocks, 256 threads: thread -> (sample tid>>4, 16-h chunk).
__global__ __launch_bounds__(256) void hidden_kernel(
    const float* __restrict__ values, const float* __restrict__ means,
    const float* __restrict__ stds, const int* __restrict__ head_idx,
    const float* __restrict__ w1, const float* __restrict__ b1,
    __bf16* __restrict__ hidden, int* __restrict__ counts)
{
    const int tid = threadIdx.x;
    const int s  = blockIdx.x * 16 + (tid >> 4);
    const int h0 = (tid & 15) * 16;
    const float z = norm_clip(values[s], means[s], stds[s]);
    alignas(16) __bf16 g[16];
#pragma unroll
    for (int i = 0; i < 16; i += 4) {
        const float4 wv = *reinterpret_cast<const float4*>(w1 + h0 + i);
        const float4 bv = *reinterpret_cast<const float4*>(b1 + h0 + i);
        g[i + 0] = (__bf16)gelu_exact(fmaf(z, wv.x, bv.x));
        g[i + 1] = (__bf16)gelu_exact(fmaf(z, wv.y, bv.y));
        g[i + 2] = (__bf16)gelu_exact(fmaf(z, wv.z, bv.z));
        g[i + 3] = (__bf16)gelu_exact(fmaf(z, wv.w, bv.w));
    }
    uint4* dst = reinterpret_cast<uint4*>(hidden + (size_t)s * HH + h0);
    const uint4* gg = reinterpret_cast<const uint4*>(g);
    dst[0] = gg[0];
    dst[1] = gg[1];
    if ((tid & 15) == 0) atomicAdd(&counts[head_idx[s]], 1);
}

// Kernel 2: exclusive scan over K=100 counts (single 128-thread block).
__global__ __launch_bounds__(128) void scan_kernel(
    const int* __restrict__ counts, int* __restrict__ offsets,
    int* __restrict__ cursor)
{
    __shared__ int buf[128];
    const int t = threadIdx.x;
    const int v = (t < KK) ? counts[t] : 0;
    buf[t] = v;
    __syncthreads();
    for (int d = 1; d < 128; d <<= 1) {
        int x = (t >= d) ? buf[t - d] : 0;
        __syncthreads();
        buf[t] += x;
        __syncthreads();
    }
    if (t < KK) {
        int excl = buf[t] - v;
        offsets[t] = excl;
        cursor[t]  = excl;
        if (t == KK - 1) offsets[KK] = buf[t];
    }
}

// Kernel 3: scatter sample ids into per-head buckets.
// Bucket ORDER is nondeterministic but each sample's output row depends only
// on its own data + fixed k-loop order -> output values are deterministic.
__global__ __launch_bounds__(256) void scatter_kernel(
    const int* __restrict__ head_idx, int* __restrict__ cursor,
    int* __restrict__ bucket)
{
    const int b = blockIdx.x * blockDim.x + threadIdx.x;
    if (b < BB) {
        int pos = atomicAdd(&cursor[head_idx[b]], 1);
        bucket[pos] = b;
    }
}

// Kernel 4: bucketed GEMM via bf16 MFMA 16x16x32.
// grid = (K, MAXT). Block 256 thr = 4 waves; wave w -> e-slice [64w, 64w+64).
// Per (head, 16-sample tile): A = hidden tile (LDS, XOR-swizzled),
// B = W rows straight from global fp32, cvt to bf16 in-flight.
__global__ __launch_bounds__(256) void head_gemm_mfma(
    const __bf16* __restrict__ hidden, const int* __restrict__ bucket,
    const int* __restrict__ offsets, const float* __restrict__ W_heads,
    const float* __restrict__ b_heads, float* __restrict__ out)
{
    const int k    = blockIdx.x;
    const int beg  = offsets[k];
    const int nk   = offsets[k + 1] - beg;
    const int tid  = threadIdx.x;
    const int wave = tid >> 6;
    const int lane = tid & 63;
    const int col16 = lane & 15;     // e within 16-frag / A row
    const int kch   = lane >> 4;     // k-chunk group
    const int wave_e = wave * 64;
    const float* __restrict__ Wk = W_heads + (size_t)k * (HH * EE);

    __shared__ __align__(16) __bf16 A_lds[16 * HH];  // 8 KB
    __shared__ int sids[16];

    for (int t = blockIdx.y; t * 16 < nk; t += gridDim.y) {
        __syncthreads();   // protect A_lds/sids from previous iteration readers
        if (tid < 16) {
            int idx = t * 16 + tid;
            if (idx >= nk) idx = nk - 1;   // clamp; masked at store
            sids[tid] = bucket[beg + idx];
        }
        __syncthreads();
        {   // stage A tile: 16 samples x 256 h bf16, 16B chunks, XOR swizzle
            const int s = tid >> 4, c = tid & 15;
            const uint4* src = reinterpret_cast<const uint4*>(hidden + (size_t)sids[s] * HH);
            const uint4 v0 = src[c];
            const uint4 v1 = src[c + 16];
            char* basep = reinterpret_cast<char*>(A_lds) + s * 512;
            *reinterpret_cast<uint4*>(basep + ((c        ^ (s & 7)) * 16)) = v0;
            *reinterpret_cast<uint4*>(basep + (((c + 16) ^ (s & 7)) * 16)) = v1;
        }
        __syncthreads();

        f32x4 acc[4];
#pragma unroll
        for (int nf = 0; nf < 4; ++nf) {
            const float bv = b_heads[k * EE + wave_e + nf * 16 + col16];
            acc[nf] = (f32x4){bv, bv, bv, bv};
        }

        const char* arow = reinterpret_cast<const char*>(A_lds) + col16 * 512;
#pragma unroll
        for (int kk = 0; kk < 8; ++kk) {
            // A-frag: row = lane&15, k = kk*32 + kch*8 + j  (8 consecutive bf16)
            const bf16x8 a = *reinterpret_cast<const bf16x8*>(
                arow + (((kk * 4 + kch) ^ (lane & 7)) * 16));
            const float* wbase = Wk + (size_t)(kk * 32 + kch * 8) * EE + wave_e + col16;
#pragma unroll
            for (int nf = 0; nf < 4; ++nf) {
                const float* wp = wbase + nf * 16;
                bf16x8 b;
#pragma unroll
                for (int j = 0; j < 8; ++j) b[j] = (__bf16)wp[j * EE];
                acc[nf] = __builtin_amdgcn_mfma_f32_16x16x32_bf16(a, b, acc[nf], 0, 0, 0);
            }
        }

        // D layout: col = lane&15, row = (lane>>4)*4 + reg
#pragma unroll
        for (int r = 0; r < 4; ++r) {
            const int srow = kch * 4 + r;
            if (t * 16 + srow < nk) {
                float* op = out + (size_t)sids[srow] * EE + wave_e + col16;
#pragma unroll
                for (int nf = 0; nf < 4; ++nf) op[nf * 16] = acc[nf][r];
            }
        }
    }
}

// Fallback (only if ws too small): one block per sample, fp32.
__global__ __launch_bounds__(256) void fallback_kernel(
    const float* __restrict__ values, const float* __restrict__ means,
    const float* __restrict__ stds, const int* __restrict__ head_idx,
    const float* __restrict__ w1, const float* __restrict__ b1,
    const float* __restrict__ W_heads, const float* __restrict__ b_heads,
    float* __restrict__ out)
{
    __shared__ float hid[HH];
    const int b = blockIdx.x;
    const int t = threadIdx.x;
    const float z = norm_clip(values[b], means[b], stds[b]);
    hid[t] = gelu_exact(fmaf(z, w1[t], b1[t]));
    __syncthreads();
    const int k = head_idx[b];
    const float* __restrict__ Wk = W_heads + (size_t)k * (HH * EE);
    float acc = b_heads[k * EE + t];
    for (int h = 0; h < HH; ++h) acc = fmaf(hid[h], Wk[h * EE + t], acc);
    out[(size_t)b * EE + t] = acc;
}

extern "C" void kernel_launch(void* const* d_in, const int* in_sizes, int n_in,
                              void* d_out, int out_size, void* d_ws, size_t ws_size,
                              hipStream_t stream)
{
    const float* values   = (const float*)d_in[0];
    const float* means    = (const float*)d_in[1];
    const float* stds     = (const float*)d_in[2];
    const int*   head_idx = (const int*)d_in[3];
    const float* w1       = (const float*)d_in[4];
    const float* b1       = (const float*)d_in[5];
    const float* W_heads  = (const float*)d_in[6];
    const float* b_heads  = (const float*)d_in[7];
    float* out = (float*)d_out;

    // Workspace layout (bytes):
    //   [0,512)      counts (K ints)
    //   [512,1024)   cursor (K ints)
    //   [1024,2048)  offsets (K+1 ints)
    //   [2048,32768) bucket (B ints)
    //   [32768,...)  hidden (B*H bf16 = 2 MB)
    const size_t need = 32768 + (size_t)BB * HH * sizeof(__bf16);
    if (ws_size >= need) {
        char* ws = (char*)d_ws;
        int*    counts  = (int*)(ws + 0);
        int*    cursor  = (int*)(ws + 512);
        int*    offsets = (int*)(ws + 1024);
        int*    bucket  = (int*)(ws + 2048);
        __bf16* hidden  = (__bf16*)(ws + 32768);

        hipMemsetAsync(counts, 0, 512, stream);
        hidden_kernel<<<BB / 16, 256, 0, stream>>>(values, means, stds, head_idx,
                                                   w1, b1, hidden, counts);
        scan_kernel<<<1, 128, 0, stream>>>(counts, offsets, cursor);
        scatter_kernel<<<(BB + 255) / 256, 256, 0, stream>>>(head_idx, cursor, bucket);
        head_gemm_mfma<<<dim3(KK, MAXT), 256, 0, stream>>>(hidden, bucket, offsets,
                                                           W_heads, b_heads, out);
    } else {
        fallback_kernel<<<BB, 256, 0, stream>>>(values, means, stds, head_idx,
                                                w1, b1, W_heads, b_heads, out);
    }
}

// Round 3
// 26.751 us; speedup vs baseline: 3.7947x; 1.6644x over previous
//
#include <hip/hip_runtime.h>
#include <hip/hip_bf16.h>
#include <math.h>

// Problem constants (match reference: B=4096, H=256, E=256, K=100)
#define BB 4096
#define HH 256
#define EE 256
#define KK 100
#define MAXT 5   // s-tile blocks per head (covers nk<=80; loop handles more)

typedef __bf16 bf16x8 __attribute__((ext_vector_type(8)));
typedef float  f32x4  __attribute__((ext_vector_type(4)));

__device__ __forceinline__ float gelu_exact(float x) {
    return 0.5f * x * (1.0f + erff(x * 0.70710678118654752f));
}

__device__ __forceinline__ float norm_clip(float v, float m, float sd) {
    float z = (v - m) / fmaxf(sd, 1e-8f);
    return fminf(5.0f, fmaxf(-5.0f, z));
}

// Kernel 1 (fused): blocks 0..BB/16-1 compute hidden = gelu(z*w1+b1) in bf16;
// block BB/16 does histogram -> exclusive scan -> bucket scatter, all in LDS
// (no pre-zeroed global memory needed -> no memset graph node).
__global__ __launch_bounds__(256) void hidden_prep_kernel(
    const float* __restrict__ values, const float* __restrict__ means,
    const float* __restrict__ stds, const int* __restrict__ head_idx,
    const float* __restrict__ w1, const float* __restrict__ b1,
    __bf16* __restrict__ hidden, int* __restrict__ offsets,
    int* __restrict__ bucket)
{
    const int tid = threadIdx.x;

    if (blockIdx.x < BB / 16) {
        // ---- hidden path: 16 samples x 256 h per block ----
        const int s  = blockIdx.x * 16 + (tid >> 4);
        const int h0 = (tid & 15) * 16;
        const float z = norm_clip(values[s], means[s], stds[s]);
        alignas(16) __bf16 g[16];
#pragma unroll
        for (int i = 0; i < 16; i += 4) {
            const float4 wv = *reinterpret_cast<const float4*>(w1 + h0 + i);
            const float4 bv = *reinterpret_cast<const float4*>(b1 + h0 + i);
            g[i + 0] = (__bf16)gelu_exact(fmaf(z, wv.x, bv.x));
            g[i + 1] = (__bf16)gelu_exact(fmaf(z, wv.y, bv.y));
            g[i + 2] = (__bf16)gelu_exact(fmaf(z, wv.z, bv.z));
            g[i + 3] = (__bf16)gelu_exact(fmaf(z, wv.w, bv.w));
        }
        uint4* dst = reinterpret_cast<uint4*>(hidden + (size_t)s * HH + h0);
        const uint4* gg = reinterpret_cast<const uint4*>(g);
        dst[0] = gg[0];
        dst[1] = gg[1];
        return;
    }

    // ---- prep path: one block. histogram + scan + scatter in LDS ----
    __shared__ int cnt[KK];
    __shared__ int cur[KK];
    __shared__ int buf[128];

    if (tid < KK) cnt[tid] = 0;
    __syncthreads();

    int hk[BB / 256];   // cache this thread's head ids (16 per thread)
#pragma unroll
    for (int i = 0; i < BB / 256; ++i) {
        const int b = i * 256 + tid;
        hk[i] = head_idx[b];
        atomicAdd(&cnt[hk[i]], 1);
    }
    __syncthreads();

    // Hillis-Steele inclusive scan over 128 slots (>= KK)
    const int v = (tid < KK) ? cnt[tid] : 0;
    if (tid < 128) buf[tid] = v;
    __syncthreads();
    for (int d = 1; d < 128; d <<= 1) {
        int x = 0;
        if (tid < 128 && tid >= d) x = buf[tid - d];
        __syncthreads();
        if (tid < 128) buf[tid] += x;
        __syncthreads();
    }
    if (tid < KK) {
        const int excl = buf[tid] - v;
        offsets[tid] = excl;
        cur[tid] = excl;
        if (tid == KK - 1) offsets[KK] = buf[tid];
    }
    __syncthreads();

    // scatter: bucket order nondeterministic; output values don't depend on it
#pragma unroll
    for (int i = 0; i < BB / 256; ++i) {
        const int b = i * 256 + tid;
        const int pos = atomicAdd(&cur[hk[i]], 1);
        bucket[pos] = b;
    }
}

// Kernel 2: bucketed GEMM via bf16 MFMA 16x16x32.
// grid = (K, MAXT). Block 256 thr = 4 waves; wave w -> e-slice [64w, 64w+64).
// Per (head, 16-sample tile): A = hidden tile (LDS, XOR-swizzled),
// B = W rows straight from global fp32, cvt to bf16 in-flight.
__global__ __launch_bounds__(256) void head_gemm_mfma(
    const __bf16* __restrict__ hidden, const int* __restrict__ bucket,
    const int* __restrict__ offsets, const float* __restrict__ W_heads,
    const float* __restrict__ b_heads, float* __restrict__ out)
{
    const int k    = blockIdx.x;
    const int beg  = offsets[k];
    const int nk   = offsets[k + 1] - beg;
    const int tid  = threadIdx.x;
    const int wave = tid >> 6;
    const int lane = tid & 63;
    const int col16 = lane & 15;     // e within 16-frag / A row
    const int kch   = lane >> 4;     // k-chunk group
    const int wave_e = wave * 64;
    const float* __restrict__ Wk = W_heads + (size_t)k * (HH * EE);

    __shared__ __align__(16) __bf16 A_lds[16 * HH];  // 8 KB
    __shared__ int sids[16];

    for (int t = blockIdx.y; t * 16 < nk; t += gridDim.y) {
        __syncthreads();   // protect A_lds/sids from previous iteration readers
        if (tid < 16) {
            int idx = t * 16 + tid;
            if (idx >= nk) idx = nk - 1;   // clamp; masked at store
            sids[tid] = bucket[beg + idx];
        }
        __syncthreads();
        {   // stage A tile: 16 samples x 256 h bf16, 16B chunks, XOR swizzle
            const int s = tid >> 4, c = tid & 15;
            const uint4* src = reinterpret_cast<const uint4*>(hidden + (size_t)sids[s] * HH);
            const uint4 v0 = src[c];
            const uint4 v1 = src[c + 16];
            char* basep = reinterpret_cast<char*>(A_lds) + s * 512;
            *reinterpret_cast<uint4*>(basep + ((c        ^ (s & 7)) * 16)) = v0;
            *reinterpret_cast<uint4*>(basep + (((c + 16) ^ (s & 7)) * 16)) = v1;
        }
        __syncthreads();

        f32x4 acc[4];
#pragma unroll
        for (int nf = 0; nf < 4; ++nf) {
            const float bv = b_heads[k * EE + wave_e + nf * 16 + col16];
            acc[nf] = (f32x4){bv, bv, bv, bv};
        }

        const char* arow = reinterpret_cast<const char*>(A_lds) + col16 * 512;
#pragma unroll
        for (int kk = 0; kk < 8; ++kk) {
            // A-frag: row = lane&15, k = kk*32 + kch*8 + j  (8 consecutive bf16)
            const bf16x8 a = *reinterpret_cast<const bf16x8*>(
                arow + (((kk * 4 + kch) ^ (lane & 7)) * 16));
            const float* wbase = Wk + (size_t)(kk * 32 + kch * 8) * EE + wave_e + col16;
#pragma unroll
            for (int nf = 0; nf < 4; ++nf) {
                const float* wp = wbase + nf * 16;
                bf16x8 b;
#pragma unroll
                for (int j = 0; j < 8; ++j) b[j] = (__bf16)wp[j * EE];
                acc[nf] = __builtin_amdgcn_mfma_f32_16x16x32_bf16(a, b, acc[nf], 0, 0, 0);
            }
        }

        // D layout: col = lane&15, row = (lane>>4)*4 + reg
#pragma unroll
        for (int r = 0; r < 4; ++r) {
            const int srow = kch * 4 + r;
            if (t * 16 + srow < nk) {
                float* op = out + (size_t)sids[srow] * EE + wave_e + col16;
#pragma unroll
                for (int nf = 0; nf < 4; ++nf) op[nf * 16] = acc[nf][r];
            }
        }
    }
}

// Fallback (only if ws too small): one block per sample, fp32.
__global__ __launch_bounds__(256) void fallback_kernel(
    const float* __restrict__ values, const float* __restrict__ means,
    const float* __restrict__ stds, const int* __restrict__ head_idx,
    const float* __restrict__ w1, const float* __restrict__ b1,
    const float* __restrict__ W_heads, const float* __restrict__ b_heads,
    float* __restrict__ out)
{
    __shared__ float hid[HH];
    const int b = blockIdx.x;
    const int t = threadIdx.x;
    const float z = norm_clip(values[b], means[b], stds[b]);
    hid[t] = gelu_exact(fmaf(z, w1[t], b1[t]));
    __syncthreads();
    const int k = head_idx[b];
    const float* __restrict__ Wk = W_heads + (size_t)k * (HH * EE);
    float acc = b_heads[k * EE + t];
    for (int h = 0; h < HH; ++h) acc = fmaf(hid[h], Wk[h * EE + t], acc);
    out[(size_t)b * EE + t] = acc;
}

extern "C" void kernel_launch(void* const* d_in, const int* in_sizes, int n_in,
                              void* d_out, int out_size, void* d_ws, size_t ws_size,
                              hipStream_t stream)
{
    const float* values   = (const float*)d_in[0];
    const float* means    = (const float*)d_in[1];
    const float* stds     = (const float*)d_in[2];
    const int*   head_idx = (const int*)d_in[3];
    const float* w1       = (const float*)d_in[4];
    const float* b1       = (const float*)d_in[5];
    const float* W_heads  = (const float*)d_in[6];
    const float* b_heads  = (const float*)d_in[7];
    float* out = (float*)d_out;

    // Workspace layout (bytes):
    //   [0,1024)     offsets (K+1 ints)
    //   [1024,17408) bucket (B ints)
    //   [32768,...)  hidden (B*H bf16 = 2 MB)
    const size_t need = 32768 + (size_t)BB * HH * sizeof(__bf16);
    if (ws_size >= need) {
        char* ws = (char*)d_ws;
        int*    offsets = (int*)(ws + 0);
        int*    bucket  = (int*)(ws + 1024);
        __bf16* hidden  = (__bf16*)(ws + 32768);

        hidden_prep_kernel<<<BB / 16 + 1, 256, 0, stream>>>(
            values, means, stds, head_idx, w1, b1, hidden, offsets, bucket);
        head_gemm_mfma<<<dim3(KK, MAXT), 256, 0, stream>>>(
            hidden, bucket, offsets, W_heads, b_heads, out);
    } else {
        fallback_kernel<<<BB, 256, 0, stream>>>(values, means, stds, head_idx,
                                                w1, b1, W_heads, b_heads, out);
    }
}